// Round 1
// baseline (155.630 us; speedup 1.0000x reference)
//
#include <hip/hip_runtime.h>

// Problem constants (from reference: B=32, C=256, H=W=96)
constexpr int CDIM  = 256;
constexpr int HWSZ  = 9216;            // 96*96
constexpr int BSZ   = 32;
constexpr int KRANK = 2764;            // int(0.3 * 9216)

// ---------------------------------------------------------------------------
// Kernel 1: x[b,s] = sum_c z[b,c,s] * phi_w[c] + phi_b
// Grid: 2304 blocks x 128 threads (exactly 9 blocks/CU on 256 CUs).
// Per c-iteration each wave reads 256B contiguous (perfect coalescing).
__global__ __launch_bounds__(128) void k_phi(
    const float* __restrict__ z, const float* __restrict__ phi_w,
    const float* __restrict__ phi_b, float* __restrict__ x)
{
    __shared__ float w[CDIM];
    const int tid = threadIdx.x;
    w[tid]       = phi_w[tid];
    w[tid + 128] = phi_w[tid + 128];
    __syncthreads();

    const int blk = blockIdx.x;            // 0..2303
    const int b   = blk / 72;              // 72 blocks per batch
    const int s   = (blk % 72) * 128 + tid;

    const float* zp = z + (size_t)b * CDIM * HWSZ + s;
    float acc = 0.f;
    #pragma unroll 16
    for (int c = 0; c < CDIM; ++c) {
        acc = fmaf(zp[(size_t)c * HWSZ], w[c], acc);
    }
    x[b * HWSZ + s] = acc + phi_b[0];
}

// ---------------------------------------------------------------------------
// Kernel 2: per-batch exact k-th largest of x[b,:] via 4-pass radix select.
// Keys: order-preserving uint transform of float. One block per batch.
__global__ __launch_bounds__(256) void k_select(
    const float* __restrict__ x, float* __restrict__ thresh)
{
    __shared__ unsigned int keys[HWSZ];    // 36 KB
    __shared__ unsigned int hist[256];
    __shared__ unsigned int s_prefix, s_k;

    const int b   = blockIdx.x;
    const int tid = threadIdx.x;
    const float* xb = x + b * HWSZ;

    for (int i = tid; i < HWSZ; i += 256) {
        unsigned int u = __float_as_uint(xb[i]);
        keys[i] = (u & 0x80000000u) ? ~u : (u | 0x80000000u);  // ascending order
    }
    if (tid == 0) { s_prefix = 0u; s_k = KRANK; }
    __syncthreads();

    // mask of bytes ABOVE byte p (already-decided prefix bytes)
    const unsigned int pmask_tab[4] = {0xFFFFFF00u, 0xFFFF0000u, 0xFF000000u, 0x00000000u};

    for (int p = 3; p >= 0; --p) {
        hist[tid] = 0u;
        __syncthreads();
        const unsigned int pmask  = pmask_tab[p];
        const unsigned int prefix = s_prefix;
        for (int i = tid; i < HWSZ; i += 256) {
            unsigned int key = keys[i];
            if ((key & pmask) == prefix)
                atomicAdd(&hist[(key >> (8 * p)) & 0xFFu], 1u);
        }
        __syncthreads();
        if (tid == 0) {
            unsigned int k = s_k, cum = 0u;
            int bin = 255;
            for (; bin > 0; --bin) {
                if (cum + hist[bin] >= k) break;
                cum += hist[bin];
            }
            s_k = k - cum;                                    // rank within bin
            s_prefix = prefix | ((unsigned int)bin << (8 * p));
        }
        __syncthreads();
    }

    if (tid == 0) {
        unsigned int key = s_prefix;
        unsigned int u = (key & 0x80000000u) ? (key & 0x7FFFFFFFu) : ~key;
        thresh[b] = __uint_as_float(u);                       // exact k-th largest
    }
}

// ---------------------------------------------------------------------------
// Kernel 3: gap[b,c] = (1/HW) * sum_s z[b,c,s] * (x[b,s] > thresh[b])
// One block per (b,c); float4 loads of the contiguous row; x row is L2-hot.
__global__ __launch_bounds__(256) void k_gap(
    const float* __restrict__ z, const float* __restrict__ x,
    const float* __restrict__ thresh, float* __restrict__ gap)
{
    const int c = blockIdx.x, b = blockIdx.y, tid = threadIdx.x;
    const float th = thresh[b];
    const float* zp = z + ((size_t)b * CDIM + c) * HWSZ;
    const float* xp = x + b * HWSZ;

    float acc = 0.f;
    #pragma unroll
    for (int k = 0; k < 9; ++k) {
        const int s = (tid + k * 256) * 4;                    // covers 0..9212
        const float4 v  = *reinterpret_cast<const float4*>(zp + s);
        const float4 xv = *reinterpret_cast<const float4*>(xp + s);
        acc += (xv.x > th) ? v.x : 0.f;
        acc += (xv.y > th) ? v.y : 0.f;
        acc += (xv.z > th) ? v.z : 0.f;
        acc += (xv.w > th) ? v.w : 0.f;
    }

    __shared__ float red[256];
    red[tid] = acc;
    __syncthreads();
    for (int off = 128; off > 0; off >>= 1) {
        if (tid < off) red[tid] += red[tid + off];
        __syncthreads();
    }
    if (tid == 0) gap[b * CDIM + c] = red[0] * (1.0f / HWSZ);
}

// ---------------------------------------------------------------------------
// Kernel 4: out[b,i] = sum_c gap[b,c] * mlp_w[i,c] + mlp_b[i]
__global__ __launch_bounds__(256) void k_mlp(
    const float* __restrict__ gap, const float* __restrict__ mlp_w,
    const float* __restrict__ mlp_b, float* __restrict__ out)
{
    const int b = blockIdx.x, i = threadIdx.x;
    __shared__ float g[CDIM];
    g[i] = gap[b * CDIM + i];
    __syncthreads();

    const float* wrow = mlp_w + (size_t)i * CDIM;
    float acc = mlp_b[i];
    #pragma unroll 8
    for (int c = 0; c < CDIM; ++c) acc = fmaf(g[c], wrow[c], acc);
    out[b * CDIM + i] = acc;
}

// ---------------------------------------------------------------------------
extern "C" void kernel_launch(void* const* d_in, const int* in_sizes, int n_in,
                              void* d_out, int out_size, void* d_ws, size_t ws_size,
                              hipStream_t stream)
{
    const float* z     = (const float*)d_in[0];
    const float* phi_w = (const float*)d_in[1];
    const float* phi_b = (const float*)d_in[2];
    const float* mlp_w = (const float*)d_in[3];
    const float* mlp_b = (const float*)d_in[4];
    float* out = (float*)d_out;

    // workspace layout (all fully written before read; ~1.2 MB total)
    float* x      = (float*)d_ws;          // B*HW floats
    float* thresh = x + BSZ * HWSZ;        // B floats
    float* gap    = thresh + BSZ;          // B*C floats

    k_phi   <<<dim3(BSZ * 72), 128, 0, stream>>>(z, phi_w, phi_b, x);
    k_select<<<dim3(BSZ),      256, 0, stream>>>(x, thresh);
    k_gap   <<<dim3(CDIM, BSZ),256, 0, stream>>>(z, x, thresh, gap);
    k_mlp   <<<dim3(BSZ),      256, 0, stream>>>(gap, mlp_w, mlp_b, out);
}

// Round 2
// 127.807 us; speedup vs baseline: 1.2177x; 1.2177x over previous
//
#include <hip/hip_runtime.h>

// Problem constants (from reference: B=32, C=256, H=W=96)
constexpr int CDIM  = 256;
constexpr int HWSZ  = 9216;            // 96*96
constexpr int BSZ   = 32;
constexpr int KRANK = 2764;            // int(0.3 * 9216)

// ---------------------------------------------------------------------------
// Kernel 1: x[b,s] = sum_c z[b,c,s] * phi_w[c] + phi_b
// Grid: 2304 blocks x 128 threads (exactly 9 blocks/CU on 256 CUs).
__global__ __launch_bounds__(128) void k_phi(
    const float* __restrict__ z, const float* __restrict__ phi_w,
    const float* __restrict__ phi_b, float* __restrict__ x)
{
    __shared__ float w[CDIM];
    const int tid = threadIdx.x;
    w[tid]       = phi_w[tid];
    w[tid + 128] = phi_w[tid + 128];
    __syncthreads();

    const int blk = blockIdx.x;            // 0..2303
    const int b   = blk / 72;              // 72 blocks per batch
    const int s   = (blk % 72) * 128 + tid;

    const float* zp = z + (size_t)b * CDIM * HWSZ + s;
    float acc = 0.f;
    #pragma unroll 16
    for (int c = 0; c < CDIM; ++c) {
        acc = fmaf(zp[(size_t)c * HWSZ], w[c], acc);
    }
    x[b * HWSZ + s] = acc + phi_b[0];
}

// ---------------------------------------------------------------------------
// Kernel 2: per-batch exact k-th largest of x[b,:].
// Value-linear bucketing (4096 bins) -> parallel suffix scan -> exact
// selection among candidates in the target bin. Gaussian data spreads
// ~2.3 elems/bin -> negligible LDS atomic contention (vs byte-radix where
// the exponent byte concentrated everything into ~13 bins).
constexpr int NB       = 4096;
constexpr int CHUNK    = NB / 256;     // bins per thread in the scan
constexpr int CAND_MAX = 128;

__global__ __launch_bounds__(256) void k_select(
    const float* __restrict__ x, float* __restrict__ thresh)
{
    __shared__ float        vals[HWSZ];      // 36 KB
    __shared__ unsigned int hist[NB];        // 16 KB
    __shared__ float        s_red[8];
    __shared__ unsigned int s_suffix[256];
    __shared__ float        s_cand[CAND_MAX];
    __shared__ unsigned int s_ccount;
    __shared__ int          s_bin;
    __shared__ unsigned int s_krem, s_cnt;
    __shared__ float        s_out;

    const int b = blockIdx.x, tid = threadIdx.x;
    const float* xb = x + b * HWSZ;

    // load row + min/max
    float vmin = INFINITY, vmax = -INFINITY;
    for (int i = tid; i < HWSZ; i += 256) {
        const float v = xb[i];
        vals[i] = v;
        vmin = fminf(vmin, v);
        vmax = fmaxf(vmax, v);
    }
    for (int off = 32; off; off >>= 1) {
        vmin = fminf(vmin, __shfl_down(vmin, off));
        vmax = fmaxf(vmax, __shfl_down(vmax, off));
    }
    if ((tid & 63) == 0) { s_red[tid >> 6] = vmin; s_red[4 + (tid >> 6)] = vmax; }
    __syncthreads();
    vmin = fminf(fminf(s_red[0], s_red[1]), fminf(s_red[2], s_red[3]));
    vmax = fmaxf(fmaxf(s_red[4], s_red[5]), fmaxf(s_red[6], s_red[7]));

    float lo = vmin;
    float inv_w = 0.f;
    unsigned int krem = KRANK;
    // predicate describing the previous iteration's target bin (membership
    // filter for refinement — exact, same arithmetic as the histogram)
    int   pred_on = 0, pred_bin = 0;
    float pred_lo = 0.f, pred_inv = 0.f;
    float range = vmax - vmin;
    float result = vmin;
    int done = (range > 0.f) ? 0 : 1;

    for (int iter = 0; iter < 5 && !done; ++iter) {
        inv_w = (float)NB / range;
        for (int i = tid; i < NB; i += 256) hist[i] = 0u;
        __syncthreads();

        for (int i = tid; i < HWSZ; i += 256) {
            const float v = vals[i];
            if (pred_on) {
                int pi = (int)((v - pred_lo) * pred_inv);
                pi = max(0, min(pi, NB - 1));
                if (pi != pred_bin) continue;
            }
            int idx = (int)((v - lo) * inv_w);
            idx = max(0, min(idx, NB - 1));
            atomicAdd(&hist[idx], 1u);
        }
        __syncthreads();

        // per-thread chunk totals, then suffix scan over 256 chunk totals
        unsigned int csum = 0;
        for (int j = 0; j < CHUNK; ++j) csum += hist[tid * CHUNK + j];
        s_suffix[tid] = csum;
        __syncthreads();
        for (int off = 1; off < 256; off <<= 1) {
            const unsigned int add = (tid + off < 256) ? s_suffix[tid + off] : 0u;
            __syncthreads();
            s_suffix[tid] += add;
            __syncthreads();
        }
        const unsigned int sfx  = s_suffix[tid];
        const unsigned int sfx1 = (tid < 255) ? s_suffix[tid + 1] : 0u;
        if (sfx >= krem && sfx1 < krem) {           // exactly one thread
            unsigned int cum_above = sfx1;
            int binr = tid * CHUNK;
            for (int j = CHUNK - 1; j >= 0; --j) {
                const unsigned int h = hist[tid * CHUNK + j];
                if (cum_above + h >= krem) { binr = tid * CHUNK + j; break; }
                cum_above += h;
            }
            s_bin  = binr;
            s_krem = krem - cum_above;
            s_cnt  = hist[binr];
        }
        __syncthreads();
        const int bin = s_bin;
        const unsigned int cnt = s_cnt;
        krem = s_krem;

        if (cnt <= CAND_MAX) {
            // gather candidates of the target bin, select krem-th largest
            if (tid == 0) s_ccount = 0;
            __syncthreads();
            for (int i = tid; i < HWSZ; i += 256) {
                const float v = vals[i];
                if (pred_on) {
                    int pi = (int)((v - pred_lo) * pred_inv);
                    pi = max(0, min(pi, NB - 1));
                    if (pi != pred_bin) continue;
                }
                int idx = (int)((v - lo) * inv_w);
                idx = max(0, min(idx, NB - 1));
                if (idx == bin) {
                    const unsigned int pos = atomicAdd(&s_ccount, 1u);
                    if (pos < CAND_MAX) s_cand[pos] = v;
                }
            }
            __syncthreads();
            const int n = min(s_ccount, (unsigned int)CAND_MAX);
            if (tid < n) {
                const float v = s_cand[tid];
                int g = 0, e = 0;
                for (int j = 0; j < n; ++j) {
                    const float u = s_cand[j];
                    g += (u > v);
                    e += (u == v);
                }
                if (g < (int)krem && g + e >= (int)krem) s_out = v;
            }
            __syncthreads();
            result = s_out;
            done = 1;
        } else {
            // refine into the target bin
            pred_on = 1; pred_bin = bin; pred_lo = lo; pred_inv = inv_w;
            const float w = range / (float)NB;
            lo    = lo + (float)bin * w;
            range = w;
            __syncthreads();
        }
    }

    if (tid == 0) thresh[b] = result;
}

// ---------------------------------------------------------------------------
// Kernel 3: gap[b,c] = (1/HW) * sum_s z[b,c,s] * (x[b,s] > thresh[b])
// b is REVERSED vs k_phi's streaming order: k_phi leaves the tail of z
// (high b) resident in the 256 MiB L3; reading it first turns most of
// pass 2 into L3 hits instead of the LRU-streaming worst case.
__global__ __launch_bounds__(256) void k_gap(
    const float* __restrict__ z, const float* __restrict__ x,
    const float* __restrict__ thresh, float* __restrict__ gap)
{
    const int c = blockIdx.x, b = (BSZ - 1) - blockIdx.y, tid = threadIdx.x;
    const float th = thresh[b];
    const float* zp = z + ((size_t)b * CDIM + c) * HWSZ;
    const float* xp = x + b * HWSZ;

    float acc = 0.f;
    #pragma unroll
    for (int k = 0; k < 9; ++k) {
        const int s = (tid + k * 256) * 4;                    // covers 0..9215
        const float4 v  = *reinterpret_cast<const float4*>(zp + s);
        const float4 xv = *reinterpret_cast<const float4*>(xp + s);
        acc += (xv.x > th) ? v.x : 0.f;
        acc += (xv.y > th) ? v.y : 0.f;
        acc += (xv.z > th) ? v.z : 0.f;
        acc += (xv.w > th) ? v.w : 0.f;
    }

    for (int off = 32; off; off >>= 1) acc += __shfl_down(acc, off);
    __shared__ float r[4];
    if ((tid & 63) == 0) r[tid >> 6] = acc;
    __syncthreads();
    if (tid == 0) gap[b * CDIM + c] = (r[0] + r[1] + r[2] + r[3]) * (1.0f / HWSZ);
}

// ---------------------------------------------------------------------------
// Kernel 4: out[b,i] = sum_c gap[b,c] * mlp_w[i,c] + mlp_b[i]
__global__ __launch_bounds__(256) void k_mlp(
    const float* __restrict__ gap, const float* __restrict__ mlp_w,
    const float* __restrict__ mlp_b, float* __restrict__ out)
{
    const int b = blockIdx.x, i = threadIdx.x;
    __shared__ float g[CDIM];
    g[i] = gap[b * CDIM + i];
    __syncthreads();

    const float* wrow = mlp_w + (size_t)i * CDIM;
    float acc = mlp_b[i];
    #pragma unroll 8
    for (int c = 0; c < CDIM; ++c) acc = fmaf(g[c], wrow[c], acc);
    out[b * CDIM + i] = acc;
}

// ---------------------------------------------------------------------------
extern "C" void kernel_launch(void* const* d_in, const int* in_sizes, int n_in,
                              void* d_out, int out_size, void* d_ws, size_t ws_size,
                              hipStream_t stream)
{
    const float* z     = (const float*)d_in[0];
    const float* phi_w = (const float*)d_in[1];
    const float* phi_b = (const float*)d_in[2];
    const float* mlp_w = (const float*)d_in[3];
    const float* mlp_b = (const float*)d_in[4];
    float* out = (float*)d_out;

    // workspace layout (all fully written before read; ~1.2 MB total)
    float* x      = (float*)d_ws;          // B*HW floats
    float* thresh = x + BSZ * HWSZ;        // B floats
    float* gap    = thresh + BSZ;          // B*C floats

    k_phi   <<<dim3(BSZ * 72),  128, 0, stream>>>(z, phi_w, phi_b, x);
    k_select<<<dim3(BSZ),       256, 0, stream>>>(x, thresh);
    k_gap   <<<dim3(CDIM, BSZ), 256, 0, stream>>>(z, x, thresh, gap);
    k_mlp   <<<dim3(BSZ),       256, 0, stream>>>(gap, mlp_w, mlp_b, out);
}